// Round 5
// baseline (458.582 us; speedup 1.0000x reference)
//
#include <hip/hip_runtime.h>
#include <cstdint>

#define Hh 64
#define Tt 512
#define Dd 6
#define BB 4      // batch rows per block
#define NT 512    // threads per block (8 waves)
#define XS_STRIDE 3080   // 3072 + 8 pad words
#define PREW 512         // pre words per wave: 4 sets x 8 cols x 4 slots x 4 gates

typedef short bf16x8 __attribute__((ext_vector_type(8)));
typedef float f32x4  __attribute__((ext_vector_type(4)));

#define MF(A, B, C) C = __builtin_amdgcn_mfma_f32_16x16x32_bf16(A, B, C, 0, 0, 0)

__device__ __forceinline__ float sigm(float v){
  return __builtin_amdgcn_rcpf(1.f + __expf(-v));
}
__device__ __forceinline__ float tanh_(float v){
  return 1.f - 2.f*__builtin_amdgcn_rcpf(1.f + __expf(2.f*v));
}
__device__ __forceinline__ unsigned short f2bf(float f){
  union { float f; unsigned u; } v; v.f = f;
  unsigned r = v.u + 0x7FFFu + ((v.u >> 16) & 1u);   // RNE
  return (unsigned short)(r >> 16);
}
__device__ __forceinline__ float bf2f(unsigned short b){
  union { unsigned u; float f; } v; v.u = ((unsigned)b) << 16;
  return v.f;
}
__device__ __forceinline__ void split8(const float* w, bf16x8& hi, bf16x8& lo){
  #pragma unroll
  for (int i = 0; i < 8; ++i){
    unsigned short h_ = f2bf(w[i]);
    hi[i] = (short)h_;
    lo[i] = (short)f2bf(w[i] - bf2f(h_));
  }
}

// h stage: hsb[buf][layer] planes [16 n][64 j] bf16, byte ^= (n&7)<<4 swizzle.
// Rows 0-3 = h_hi(bs), 4-7 = h_lo(bs), 8-15 zero.
// pre (per wave): [set s][col 0..7][slot lg'][gate 0..3] floats, lg' = lg^(col&3).
//   set s = layer*2 + p;  C frag reg rg = gate rg of cell j = wid*8 + p*4 + lg.
__global__ __launch_bounds__(NT, 2)
void lstm2_mfma(const float* __restrict__ x,
                const float* __restrict__ Wih0, const float* __restrict__ Whh0,
                const float* __restrict__ bih0, const float* __restrict__ bhh0,
                const float* __restrict__ Wih1, const float* __restrict__ Whh1,
                const float* __restrict__ bih1, const float* __restrict__ bhh1,
                const float* __restrict__ W1, const float* __restrict__ b1,
                const float* __restrict__ W2, const float* __restrict__ b2,
                float* __restrict__ out)
{
  __shared__ __align__(16) float xs[BB*XS_STRIDE];   // ~49 KB
  __shared__ __align__(16) short hsb[2*2*1024];      // 8 KB
  __shared__ __align__(16) float pre[8*PREW];        // 16 KB
  __shared__ __align__(16) float h1f[BB*Hh];
  __shared__ float zs[BB*32];

  const int tid  = threadIdx.x;
  const int lane = tid & 63;
  const int wid  = tid >> 6;        // wave 0..7
  const int lr   = lane & 15;       // A frag-row / B,C col
  const int lg   = lane >> 4;       // k-group / C row-group
  const int l    = lane >> 5;       // update: layer
  const int jj   = (lane >> 2) & 7; // update: local j
  const int bs   = lane & 3;        // update: batch row
  const int jglob= wid*8 + jj;
  const int b0   = blockIdx.x * BB;

  // stage x
  #pragma unroll
  for (int bb = 0; bb < BB; ++bb){
    const float4* src = (const float4*)(x + (size_t)(b0+bb)*(Tt*Dd));
    float4* dst = (float4*)(xs + bb*XS_STRIDE);
    for (int i = tid; i < (Tt*Dd)/4; i += NT) dst[i] = src[i];
  }
  // zero h stage
  {
    int* hz = (int*)hsb;
    hz[tid] = 0; hz[tid+NT] = 0; hz[tid+2*NT] = 0; hz[tid+3*NT] = 0;
  }

  // ---- resident A-fragments, gate-interleaved row map ----
  // tile p, frag-row r -> m = (r&3)*64 + wid*8 + p*4 + (r>>2)
  // => C frag reg rg = gate rg of cell (j = wid*8 + p*4 + lg), col lr.
  bf16x8 A0[2][2][2];       // [p][kt][hi/lo]            Whh0
  bf16x8 A1[2][2][2][2];    // [p][mat ih/hh][kt][hi/lo]
  #pragma unroll
  for (int p = 0; p < 2; ++p){
    const int m = (lr&3)*64 + wid*8 + p*4 + (lr>>2);
    #pragma unroll
    for (int kt = 0; kt < 2; ++kt){
      const int off = m*64 + kt*32 + lg*8;
      float wbuf[8];
      *(float4*)&wbuf[0] = *(const float4*)&Whh0[off];
      *(float4*)&wbuf[4] = *(const float4*)&Whh0[off+4];
      split8(wbuf, A0[p][kt][0], A0[p][kt][1]);
      *(float4*)&wbuf[0] = *(const float4*)&Wih1[off];
      *(float4*)&wbuf[4] = *(const float4*)&Wih1[off+4];
      split8(wbuf, A1[p][0][kt][0], A1[p][0][kt][1]);
      *(float4*)&wbuf[0] = *(const float4*)&Whh1[off];
      *(float4*)&wbuf[4] = *(const float4*)&Whh1[off+4];
      split8(wbuf, A1[p][1][kt][0], A1[p][1][kt][1]);
    }
  }

  // update constants (cell = (l, bs, jglob))
  float bias_g[4], w0r[24];
  #pragma unroll
  for (int gt = 0; gt < 4; ++gt){
    const int row = gt*64 + jglob;
    if (l == 0){
      bias_g[gt] = bih0[row] + bhh0[row];
      #pragma unroll
      for (int d = 0; d < Dd; ++d) w0r[gt*6+d] = Wih0[row*Dd + d];
    } else {
      bias_g[gt] = bih1[row] + bhh1[row];
      #pragma unroll
      for (int d = 0; d < Dd; ++d) w0r[gt*6+d] = 0.f;
    }
  }

  // loop-invariant offsets
  const int boff0 = (lr*128 + lg*16)      ^ ((lr&7)<<4);   // B kt=0 (bytes)
  const int boff1 = (lr*128 + 64 + lg*16) ^ ((lr&7)<<4);   // B kt=1
  const int whi   = (bs*128     + jglob*2) ^ (bs<<4);      // h_hi write (bytes)
  const int wlo   = ((bs+4)*128 + jglob*2) ^ ((bs+4)<<4);  // h_lo write
  float* preW = pre + wid*PREW;
  const int pwb  = lr*16 + ((lg ^ (lr&3)) << 2);           // + s*128 per set (words)
  const int lgp  = ((jj&3) ^ (bs&3)) << 2;
  const int sbase= (l*2 + (jj>>2))*128;
  const int prh  = sbase + bs*16 + lgp;                    // hi col read (words)
  const int prl  = sbase + (bs+4)*16 + lgp;                // lo col read

  float creg = 0.f;
  __syncthreads();

  // prologue: h0(0) from x(0) only
  if (l == 0){
    const float2* xv2 = (const float2*)(xs + bs*XS_STRIDE);
    float2 xa = xv2[0], xb = xv2[1], xc = xv2[2];
    float s[4];
    #pragma unroll
    for (int gt = 0; gt < 4; ++gt)
      s[gt] = bias_g[gt] + w0r[gt*6+0]*xa.x + w0r[gt*6+1]*xa.y
            + w0r[gt*6+2]*xb.x + w0r[gt*6+3]*xb.y
            + w0r[gt*6+4]*xc.x + w0r[gt*6+5]*xc.y;
    float iv = sigm(s[0]), fv = sigm(s[1]), gv = tanh_(s[2]), ov = sigm(s[3]);
    creg = fv*creg + iv*gv;
    float hval = ov * tanh_(creg);
    unsigned short hh = f2bf(hval);
    unsigned short hl = f2bf(hval - bf2f(hh));
    char* hw = (char*)hsb;
    *(short*)(hw + whi) = (short)hh;
    *(short*)(hw + wlo) = (short)hl;
  }
  __syncthreads();

  #pragma unroll 1
  for (int t = 0; t < Tt; ++t){
    const int buf = t & 1;
    const char* hb = (const char*)hsb + buf*4096;
    bf16x8 b00 = *(const bf16x8*)(hb + boff0);
    bf16x8 b01 = *(const bf16x8*)(hb + boff1);
    bf16x8 b10 = *(const bf16x8*)(hb + 2048 + boff0);
    bf16x8 b11 = *(const bf16x8*)(hb + 2048 + boff1);

    f32x4 a00 = {0,0,0,0}, a01 = {0,0,0,0}, a10 = {0,0,0,0}, a11 = {0,0,0,0};
    // interleaved rounds: 4 independent accumulator chains
    MF(A0[0][0][0], b00, a00); MF(A0[1][0][0], b00, a01);
    MF(A1[0][0][0][0], b00, a10); MF(A1[1][0][0][0], b00, a11);
    MF(A0[0][1][0], b01, a00); MF(A0[1][1][0], b01, a01);
    MF(A1[0][0][1][0], b01, a10); MF(A1[1][0][1][0], b01, a11);
    MF(A0[0][0][1], b00, a00); MF(A0[1][0][1], b00, a01);
    MF(A1[0][0][0][1], b00, a10); MF(A1[1][0][0][1], b00, a11);
    MF(A0[0][1][1], b01, a00); MF(A0[1][1][1], b01, a01);
    MF(A1[0][0][1][1], b01, a10); MF(A1[1][0][1][1], b01, a11);
    MF(A1[0][1][0][0], b10, a10); MF(A1[1][1][0][0], b10, a11);
    MF(A1[0][1][1][0], b11, a10); MF(A1[1][1][1][0], b11, a11);
    MF(A1[0][1][0][1], b10, a10); MF(A1[1][1][0][1], b10, a11);
    MF(A1[0][1][1][1], b11, a10); MF(A1[1][1][1][1], b11, a11);

    // pre write: 4x ds_write_b128 (cols 0..7 only; gates consecutive)
    if (lr < 8){
      *(f32x4*)(preW + pwb)       = a00;
      *(f32x4*)(preW + pwb + 128) = a01;
      *(f32x4*)(preW + pwb + 256) = a10;
      *(f32x4*)(preW + pwb + 384) = a11;
    }

    // update: 2x ds_read_b128 (hi + lo cols), same-wave data
    if ((l == 1) | (t+1 < Tt)){
      f32x4 gh = *(const f32x4*)(preW + prh);
      f32x4 gl = *(const f32x4*)(preW + prl);
      float s0 = gh[0] + gl[0] + bias_g[0];
      float s1 = gh[1] + gl[1] + bias_g[1];
      float s2 = gh[2] + gl[2] + bias_g[2];
      float s3 = gh[3] + gl[3] + bias_g[3];
      if (l == 0){
        const float2* xv2 = (const float2*)(xs + bs*XS_STRIDE + (t+1)*Dd);
        float2 xa = xv2[0], xb = xv2[1], xc = xv2[2];
        s0 += w0r[ 0]*xa.x + w0r[ 1]*xa.y + w0r[ 2]*xb.x
            + w0r[ 3]*xb.y + w0r[ 4]*xc.x + w0r[ 5]*xc.y;
        s1 += w0r[ 6]*xa.x + w0r[ 7]*xa.y + w0r[ 8]*xb.x
            + w0r[ 9]*xb.y + w0r[10]*xc.x + w0r[11]*xc.y;
        s2 += w0r[12]*xa.x + w0r[13]*xa.y + w0r[14]*xb.x
            + w0r[15]*xb.y + w0r[16]*xc.x + w0r[17]*xc.y;
        s3 += w0r[18]*xa.x + w0r[19]*xa.y + w0r[20]*xb.x
            + w0r[21]*xb.y + w0r[22]*xc.x + w0r[23]*xc.y;
      }
      float iv = sigm(s0), fv = sigm(s1), gv = tanh_(s2), ov = sigm(s3);
      creg = fv*creg + iv*gv;
      float hval = ov * tanh_(creg);
      if ((l == 1) & (t == Tt-1)) h1f[bs*64 + jglob] = hval;
      unsigned short hh = f2bf(hval);
      unsigned short hl = f2bf(hval - bf2f(hh));
      char* hw = (char*)hsb + (buf^1)*4096 + l*2048;
      *(short*)(hw + whi) = (short)hh;
      *(short*)(hw + wlo) = (short)hl;
    }
    __syncthreads();
  }

  // ---- MLP head ----
  if (tid < BB*32){
    const int bsh = tid >> 5, m = tid & 31;
    float acc = b1[m];
    #pragma unroll
    for (int j = 0; j < Hh; ++j) acc += W1[m*Hh + j] * h1f[bsh*64 + j];
    zs[bsh*32 + m] = fmaxf(acc, 0.f);
  }
  __syncthreads();
  if (tid < BB){
    float acc = b2[0];
    #pragma unroll
    for (int m = 0; m < 32; ++m) acc += W2[m] * zs[tid*32 + m];
    out[b0 + tid] = sigm(acc);
  }
}

extern "C" void kernel_launch(void* const* d_in, const int* in_sizes, int n_in,
                              void* d_out, int out_size, void* d_ws, size_t ws_size,
                              hipStream_t stream) {
  const float* x    = (const float*)d_in[0];
  const float* Wih0 = (const float*)d_in[1];
  const float* Whh0 = (const float*)d_in[2];
  const float* bih0 = (const float*)d_in[3];
  const float* bhh0 = (const float*)d_in[4];
  const float* Wih1 = (const float*)d_in[5];
  const float* Whh1 = (const float*)d_in[6];
  const float* bih1 = (const float*)d_in[7];
  const float* bhh1 = (const float*)d_in[8];
  const float* W1   = (const float*)d_in[9];
  const float* b1   = (const float*)d_in[10];
  const float* W2   = (const float*)d_in[11];
  const float* b2   = (const float*)d_in[12];

  const int B = in_sizes[0] / (Tt*Dd);   // 1024
  dim3 grid(B / BB), block(NT);
  hipLaunchKernelGGL(lstm2_mfma, grid, block, 0, stream,
                     x, Wih0, Whh0, bih0, bhh0, Wih1, Whh1, bih1, bhh1,
                     W1, b1, W2, b2, (float*)d_out);
}

// Round 6
// 436.037 us; speedup vs baseline: 1.0517x; 1.0517x over previous
//
#include <hip/hip_runtime.h>
#include <cstdint>

#define Hh 64
#define Tt 512
#define Dd 6
#define BB 4      // batch rows per block
#define NT 512    // threads per block (8 waves)

typedef short bf16x8 __attribute__((ext_vector_type(8)));
typedef float f32x4  __attribute__((ext_vector_type(4)));

#define MF(A, B, C) C = __builtin_amdgcn_mfma_f32_16x16x32_bf16(A, B, C, 0, 0, 0)

__device__ __forceinline__ float sigm(float v){
  return __builtin_amdgcn_rcpf(1.f + __expf(-v));
}
__device__ __forceinline__ float tanh_(float v){
  return 1.f - 2.f*__builtin_amdgcn_rcpf(1.f + __expf(2.f*v));
}
__device__ __forceinline__ unsigned short f2bf(float f){
  union { float f; unsigned u; } v; v.f = f;
  unsigned r = v.u + 0x7FFFu + ((v.u >> 16) & 1u);   // RNE
  return (unsigned short)(r >> 16);
}
__device__ __forceinline__ float bf2f(unsigned short b){
  union { unsigned u; float f; } v; v.u = ((unsigned)b) << 16;
  return v.f;
}
__device__ __forceinline__ void split8(const float* w, bf16x8& hi, bf16x8& lo){
  #pragma unroll
  for (int i = 0; i < 8; ++i){
    unsigned short h_ = f2bf(w[i]);
    hi[i] = (short)h_;
    lo[i] = (short)f2bf(w[i] - bf2f(h_));
  }
}

// h stage: hsb[buf][layer] planes [16 n][64 j] bf16, byte ^= (n&7)<<4 swizzle.
// Rows 0-3 = h_hi(bs), 4-7 = h_lo(bs), 8-15 never written (B cols 8-15 -> C cols
// 8-15 = garbage, ignored by the swizzle gather).
__global__ __launch_bounds__(NT, 2)
void lstm2_mfma(const float* __restrict__ x,
                const float* __restrict__ Wih0, const float* __restrict__ Whh0,
                const float* __restrict__ bih0, const float* __restrict__ bhh0,
                const float* __restrict__ Wih1, const float* __restrict__ Whh1,
                const float* __restrict__ bih1, const float* __restrict__ bhh1,
                const float* __restrict__ W1, const float* __restrict__ b1,
                const float* __restrict__ W2, const float* __restrict__ b2,
                float* __restrict__ out)
{
  __shared__ __align__(16) short hsb[2*2*1024];   // 8 KB  [buf][layer][16][64]
  __shared__ __align__(16) float h1f[BB*Hh];      // 1 KB
  __shared__ float zs[BB*32];

  const int tid  = threadIdx.x;
  const int lane = tid & 63;
  const int wid  = tid >> 6;        // wave 0..7
  const int lr   = lane & 15;       // A frag-row / B,C col
  const int lg   = lane >> 4;       // k-group / C row-group
  const int b0   = blockIdx.x * BB;

  // update mapping: every lane owns exactly one cell
  const int u_l  = lr >> 3;         // layer
  const int u_p  = (lr >> 2) & 1;   // tile (j sub-block)
  const int u_bs = lr & 3;          // batch row
  const int u_j  = wid*8 + u_p*4 + lg;

  // zero h stage (both buffers, both layers)
  {
    int* hz = (int*)hsb;
    hz[tid] = 0; hz[tid+NT] = 0; hz[tid+2*NT] = 0; hz[tid+3*NT] = 0;
  }

  // ---- resident A-fragments (bf16 hi/lo split), gate-interleaved row map ----
  // tile p, frag-row r -> m = (r&3)*64 + wid*8 + p*4 + (r>>2)
  // => C frag reg rg = gate rg of cell (j = wid*8 + p*4 + lg), col lr.
  bf16x8 A0[2][2][2];       // [p][kt][hi/lo]            Whh0
  bf16x8 A1[2][2][2][2];    // [p][mat ih/hh][kt][hi/lo]
  #pragma unroll
  for (int p = 0; p < 2; ++p){
    const int m = (lr&3)*64 + wid*8 + p*4 + (lr>>2);
    #pragma unroll
    for (int kt = 0; kt < 2; ++kt){
      const int off = m*64 + kt*32 + lg*8;
      float wbuf[8];
      *(float4*)&wbuf[0] = *(const float4*)&Whh0[off];
      *(float4*)&wbuf[4] = *(const float4*)&Whh0[off+4];
      split8(wbuf, A0[p][kt][0], A0[p][kt][1]);
      *(float4*)&wbuf[0] = *(const float4*)&Wih1[off];
      *(float4*)&wbuf[4] = *(const float4*)&Wih1[off+4];
      split8(wbuf, A1[p][0][kt][0], A1[p][0][kt][1]);
      *(float4*)&wbuf[0] = *(const float4*)&Whh1[off];
      *(float4*)&wbuf[4] = *(const float4*)&Whh1[off+4];
      split8(wbuf, A1[p][1][kt][0], A1[p][1][kt][1]);
    }
  }

  // update-phase constants (cell = (u_l, u_bs, u_j))
  float bias_g[4], w0r[24];
  #pragma unroll
  for (int gt = 0; gt < 4; ++gt){
    const int row = gt*64 + u_j;
    if (u_l == 0){
      bias_g[gt] = bih0[row] + bhh0[row];
      #pragma unroll
      for (int d = 0; d < Dd; ++d) w0r[gt*6+d] = Wih0[row*Dd + d];
    } else {
      bias_g[gt] = bih1[row] + bhh1[row];
      #pragma unroll
      for (int d = 0; d < Dd; ++d) w0r[gt*6+d] = 0.f;
    }
  }

  // loop-invariant LDS offsets
  const int boff0 = (lr*128 + lg*16)      ^ ((lr&7)<<4);   // B kt=0 (bytes)
  const int boff1 = (lr*128 + 64 + lg*16) ^ ((lr&7)<<4);   // B kt=1
  const int whi   = (u_bs*128     + u_j*2) ^ (u_bs<<4);    // h_hi write (bytes)
  const int wlo   = ((u_bs+4)*128 + u_j*2) ^ ((u_bs+4)<<4);// h_lo write

  // x stream for this lane's batch row (float2-aligned: 6 floats/step = 24B)
  const float2* px2 = (const float2*)(x + (size_t)(b0 + u_bs) * (Tt*Dd));
  float2 xi0 = px2[0], xi1 = px2[1], xi2 = px2[2];   // x(0)
  float2 xc0 = px2[3], xc1 = px2[4], xc2 = px2[5];   // x(1)
  float2 xf0 = px2[6], xf1 = px2[7], xf2 = px2[8];   // x(2)

  float creg = 0.f;
  __syncthreads();

  // prologue: h0(0) from x(0) only (h0(-1)=0), layer-0 lanes
  if (u_l == 0){
    float s[4];
    #pragma unroll
    for (int gt = 0; gt < 4; ++gt)
      s[gt] = bias_g[gt] + w0r[gt*6+0]*xi0.x + w0r[gt*6+1]*xi0.y
            + w0r[gt*6+2]*xi1.x + w0r[gt*6+3]*xi1.y
            + w0r[gt*6+4]*xi2.x + w0r[gt*6+5]*xi2.y;
    float iv = sigm(s[0]), fv = sigm(s[1]), gv = tanh_(s[2]), ov = sigm(s[3]);
    creg = fv*creg + iv*gv;
    float hval = ov * tanh_(creg);
    unsigned short hh = f2bf(hval);
    unsigned short hl = f2bf(hval - bf2f(hh));
    char* hw = (char*)hsb;                 // buf0, layer0 plane
    *(short*)(hw + whi) = (short)hh;
    *(short*)(hw + wlo) = (short)hl;
  }
  __syncthreads();

  // steady state: at iter t, hsb[t&1] holds h0(t) (plane0) and h1(t-1) (plane1)
  #pragma unroll 2
  for (int t = 0; t < Tt; ++t){
    // prefetch x(t+3) (depth-2 pipeline; clamp keeps address valid)
    float2 xn0, xn1, xn2;
    {
      const int tl = (t+3 < Tt) ? (t+3) : (Tt-1);
      xn0 = px2[tl*3]; xn1 = px2[tl*3+1]; xn2 = px2[tl*3+2];
    }

    const int buf = t & 1;
    const char* hb = (const char*)hsb + buf*4096;
    bf16x8 b00 = *(const bf16x8*)(hb + boff0);
    bf16x8 b01 = *(const bf16x8*)(hb + boff1);
    bf16x8 b10 = *(const bf16x8*)(hb + 2048 + boff0);
    bf16x8 b11 = *(const bf16x8*)(hb + 2048 + boff1);

    f32x4 a00 = {0,0,0,0}, a01 = {0,0,0,0}, a10 = {0,0,0,0}, a11 = {0,0,0,0};
    // layer-0 chains first so their gather can overlap layer-1 MFMAs
    MF(A0[0][0][0], b00, a00); MF(A0[1][0][0], b00, a01);
    MF(A0[0][1][0], b01, a00); MF(A0[1][1][0], b01, a01);
    MF(A0[0][0][1], b00, a00); MF(A0[1][0][1], b00, a01);
    MF(A0[0][1][1], b01, a00); MF(A0[1][1][1], b01, a01);

    // L0 gather: gate = own-col + partner-col (xor 4), 1 swizzle per gate
    float g0[4];
    #pragma unroll
    for (int rg = 0; rg < 4; ++rg){
      float own = (lr & 4) ? a01[rg] : a00[rg];
      float snd = (lr & 4) ? a00[rg] : a01[rg];
      g0[rg] = own + __shfl_xor(snd, 4);
    }

    // layer-1: a1 = Wih1*h0 + Whh1*h1 accumulated in one chain per tile
    MF(A1[0][0][0][0], b00, a10); MF(A1[1][0][0][0], b00, a11);
    MF(A1[0][0][1][0], b01, a10); MF(A1[1][0][1][0], b01, a11);
    MF(A1[0][0][0][1], b00, a10); MF(A1[1][0][0][1], b00, a11);
    MF(A1[0][0][1][1], b01, a10); MF(A1[1][0][1][1], b01, a11);
    MF(A1[0][1][0][0], b10, a10); MF(A1[1][1][0][0], b10, a11);
    MF(A1[0][1][1][0], b11, a10); MF(A1[1][1][1][0], b11, a11);
    MF(A1[0][1][0][1], b10, a10); MF(A1[1][1][0][1], b10, a11);
    MF(A1[0][1][1][1], b11, a10); MF(A1[1][1][1][1], b11, a11);

    // L1 gather: col-pair sums at source lanes (xor 4), then ship to lanes 8-15 (xor 8)
    float g1[4];
    #pragma unroll
    for (int rg = 0; rg < 4; ++rg){
      float s10 = a10[rg] + __shfl_xor(a10[rg], 4);
      float s11 = a11[rg] + __shfl_xor(a11[rg], 4);
      float snd = (lr & 4) ? s11 : s10;
      g1[rg] = __shfl_xor(snd, 8);
    }

    // ---- update (one cell per lane) ----
    if ((u_l == 1) | (t+1 < Tt)){
      float s0 = ((u_l == 0) ? g0[0] : g1[0]) + bias_g[0];
      float s1 = ((u_l == 0) ? g0[1] : g1[1]) + bias_g[1];
      float s2 = ((u_l == 0) ? g0[2] : g1[2]) + bias_g[2];
      float s3 = ((u_l == 0) ? g0[3] : g1[3]) + bias_g[3];
      if (u_l == 0){
        s0 += w0r[ 0]*xc0.x + w0r[ 1]*xc0.y + w0r[ 2]*xc1.x
            + w0r[ 3]*xc1.y + w0r[ 4]*xc2.x + w0r[ 5]*xc2.y;
        s1 += w0r[ 6]*xc0.x + w0r[ 7]*xc0.y + w0r[ 8]*xc1.x
            + w0r[ 9]*xc1.y + w0r[10]*xc2.x + w0r[11]*xc2.y;
        s2 += w0r[12]*xc0.x + w0r[13]*xc0.y + w0r[14]*xc1.x
            + w0r[15]*xc1.y + w0r[16]*xc2.x + w0r[17]*xc2.y;
        s3 += w0r[18]*xc0.x + w0r[19]*xc0.y + w0r[20]*xc1.x
            + w0r[21]*xc1.y + w0r[22]*xc2.x + w0r[23]*xc2.y;
      }
      float iv = sigm(s0), fv = sigm(s1), gv = tanh_(s2), ov = sigm(s3);
      creg = fv*creg + iv*gv;
      float hval = ov * tanh_(creg);
      if ((u_l == 1) & (t == Tt-1)) h1f[u_bs*64 + u_j] = hval;
      unsigned short hh = f2bf(hval);
      unsigned short hl = f2bf(hval - bf2f(hh));
      char* hw = (char*)hsb + (buf^1)*4096 + u_l*2048;
      *(short*)(hw + whi) = (short)hh;
      *(short*)(hw + wlo) = (short)hl;
    }

    // rotate x pipeline
    xc0 = xf0; xc1 = xf1; xc2 = xf2;
    xf0 = xn0; xf1 = xn1; xf2 = xn2;

    __syncthreads();   // the ONE barrier per step (h double-buffered)
  }

  // ---- MLP head on h1(T-1) ----
  if (tid < BB*32){
    const int bsh = tid >> 5, m = tid & 31;
    float acc = b1[m];
    #pragma unroll
    for (int j = 0; j < Hh; ++j) acc += W1[m*Hh + j] * h1f[bsh*64 + j];
    zs[bsh*32 + m] = fmaxf(acc, 0.f);
  }
  __syncthreads();
  if (tid < BB){
    float acc = b2[0];
    #pragma unroll
    for (int m = 0; m < 32; ++m) acc += W2[m] * zs[tid*32 + m];
    out[b0 + tid] = sigm(acc);
  }
}

extern "C" void kernel_launch(void* const* d_in, const int* in_sizes, int n_in,
                              void* d_out, int out_size, void* d_ws, size_t ws_size,
                              hipStream_t stream) {
  const float* x    = (const float*)d_in[0];
  const float* Wih0 = (const float*)d_in[1];
  const float* Whh0 = (const float*)d_in[2];
  const float* bih0 = (const float*)d_in[3];
  const float* bhh0 = (const float*)d_in[4];
  const float* Wih1 = (const float*)d_in[5];
  const float* Whh1 = (const float*)d_in[6];
  const float* bih1 = (const float*)d_in[7];
  const float* bhh1 = (const float*)d_in[8];
  const float* W1   = (const float*)d_in[9];
  const float* b1   = (const float*)d_in[10];
  const float* W2   = (const float*)d_in[11];
  const float* b2   = (const float*)d_in[12];

  const int B = in_sizes[0] / (Tt*Dd);   // 1024
  dim3 grid(B / BB), block(NT);
  hipLaunchKernelGGL(lstm2_mfma, grid, block, 0, stream,
                     x, Wih0, Whh0, bih0, bhh0, Wih1, Whh1, bih1, bhh1,
                     W1, b1, W2, b2, (float*)d_out);
}